// Round 7
// baseline (144.439 us; speedup 1.0000x reference)
//
#include <hip/hip_runtime.h>
#include <stdint.h>

typedef _Float16 half8 __attribute__((ext_vector_type(8)));
typedef _Float16 half4 __attribute__((ext_vector_type(4)));
typedef __fp16   fp16x2 __attribute__((ext_vector_type(2)));
typedef float    floatx4 __attribute__((ext_vector_type(4)));
typedef unsigned uintx2 __attribute__((ext_vector_type(2)));

#define T_LEN 2048
#define CH 64
#define BH 32            // bs * n_heads
#define QTILE 32         // t per block: per-wave O-partial = QTILE regs/lane
#define LDP 72           // prep LDS pad (halves)
#define FRAG_BH 131072   // halves per bh per tensor (64*2048)

// ---------------- pass 1: fp32 -> fp16, reorder into MFMA fragment order ----------
// Q pre-scaled by 0.125 * rescale * log2(e) so attention does raw exp2.
// QF/KF[bh][g][ks][lane][8]: g = t(or s)>>4, element = X[c = ks*32+quad*8+j][t = g*16+l15]
// VF[bh][sl][ct][lane][4]  (16x16x16 A-frag order):
//   element = V[c = ct*16 + l15][s = sl*16 + quad*4 + e]
__global__ __launch_bounds__(256, 2)
void prep_kernel(const float* __restrict__ qkv, const float* __restrict__ rescale,
                 _Float16* __restrict__ ws)
{
    __shared__ _Float16 Qs[64][LDP];   // [t][c]
    __shared__ _Float16 Ks[64][LDP];   // [s][c]
    __shared__ _Float16 Vs[64][LDP];   // [c][s]

    const int tid  = threadIdx.x;
    const int bh   = blockIdx.y;
    const int tile = blockIdx.x;       // 64-element tile along t/s
    const int x0   = tile * 64;

    const float qscale = 0.125f * 1.4426950408889634f * rescale[0];

    const float* qp = qkv + (size_t)(bh >> 3) * (1536 * T_LEN)
                          + (size_t)(bh & 7) * (192 * T_LEN);
    const float* kp = qp + 64 * T_LEN;
    const float* vp = qp + 128 * T_LEN;

    // Q,K: 4x4 register-block transpose [c][t] -> [t][c]
    {
        const int a4 = (tid & 15) * 4;
        const int c4 = (tid >> 4) * 4;
        float4 rq[4], rk[4];
#pragma unroll
        for (int i = 0; i < 4; ++i) {
            rq[i] = *(const float4*)(qp + (size_t)(c4 + i) * T_LEN + x0 + a4);
            rk[i] = *(const float4*)(kp + (size_t)(c4 + i) * T_LEN + x0 + a4);
        }
#pragma unroll
        for (int j = 0; j < 4; ++j) {
            half4 hq, hk;
#pragma unroll
            for (int i = 0; i < 4; ++i) {
                hq[i] = (_Float16)((&rq[i].x)[j] * qscale);
                hk[i] = (_Float16)((&rk[i].x)[j]);
            }
            *(half4*)&Qs[a4 + j][c4] = hq;
            *(half4*)&Ks[a4 + j][c4] = hk;
        }
        // V natural [c][s]
        const int s4 = (tid & 15) * 4;
        const int cv = tid >> 4;
#pragma unroll
        for (int i = 0; i < 4; ++i) {
            const int c = cv + 16 * i;
            float4 r = *(const float4*)(vp + (size_t)c * T_LEN + x0 + s4);
            half4 h; h[0]=(_Float16)r.x; h[1]=(_Float16)r.y; h[2]=(_Float16)r.z; h[3]=(_Float16)r.w;
            *(half4*)&Vs[c][s4] = h;
        }
    }
    __syncthreads();

    const int lane = tid & 63, wave = tid >> 6;
    const int l15 = lane & 15, quad = lane >> 4;
    _Float16* qf = ws;
    _Float16* kf = ws + (size_t)BH * FRAG_BH;
    _Float16* vf = ws + (size_t)2 * BH * FRAG_BH;

#pragma unroll
    for (int ks = 0; ks < 2; ++ks) {
        half8 hq = *(const half8*)&Qs[wave * 16 + l15][ks * 32 + quad * 8];
        half8 hk = *(const half8*)&Ks[wave * 16 + l15][ks * 32 + quad * 8];
        const size_t gqk = (((size_t)bh * 128 + tile * 4 + wave) * 2 + ks) * 512 + lane * 8;
        *(half8*)(qf + gqk) = hq;
        *(half8*)(kf + gqk) = hk;
    }
    // V fragments: wave w handles sl = tile*4 + w (16 s values)
#pragma unroll
    for (int ct = 0; ct < 4; ++ct) {
        half4 hv = *(const half4*)&Vs[ct * 16 + l15][wave * 16 + quad * 4];
        *(half4*)(vf + (size_t)bh * FRAG_BH
                     + ((size_t)(tile * 4 + wave) * 4 + ct) * 256 + lane * 4) = hv;
    }
}

// ---------------- pass 2: attention, s-partitioned waves, barrier-free loop --------
// R6 post-mortem: structure worked (no loop LDS/barriers, in-register softmax) but
// OccupancyPercent=23% exposed the real cap: VGPR_Count=84 EXCLUDES the 64-reg AGPR
// accumulator (oacc[4][4]); 148 total on the unified gfx950 file -> 2 waves/SIMD,
// plus a 3+1 straggler phase at grid 1024. With 2 waves the matrix/VALU bursts
// can't overlap beyond the measured 77% -> the ~50us wall of every round.
// This round: QTILE 64->32. Per-wave O-partial = QTILE regs/lane, so oacc drops to
// 32 regs -> ~105 total -> 4 waves/SIMD; grid 2048 = 8 blocks/CU, 4 resident ->
// two uniform phases, no straggler. Co-resident blocks share the same bh (same K/V
// stream -> L1/L2 dedup). Known risk: L2 traffic doubles to ~1GB (~3.8 TB/s per
// XCD) - near the per-XCD L2 ceiling; XCD swizzle is what keeps it feasible.
// Epilogue LDS padded (stride 18 floats) to kill the residual 2.36M bank conflicts.
__global__ __launch_bounds__(256, 4)
void attn_kernel(const _Float16* __restrict__ ws, float* __restrict__ out)
{
    __shared__ float Os[4][32][18];    // [wave][t][c16 pad 18] reduction chunk
    __shared__ float Lred[4][32];
    __shared__ float Lfin[32];

    const int tid  = threadIdx.x;
    const int wave = tid >> 6;
    const int lane = tid & 63;
    const int l15  = lane & 15;
    const int quad = lane >> 4;

    const int bid  = blockIdx.x;        // 0..2047
    const int xcd  = bid & 7;
    const int slot = bid >> 3;          // 0..255
    const int bh   = (slot & 3) * 8 + xcd;
    const int tile = slot >> 2;         // 0..63
    const int t0   = tile * QTILE;

    const _Float16* qf = ws;
    const _Float16* kf = ws + (size_t)BH * FRAG_BH;
    const _Float16* vf = ws + (size_t)2 * BH * FRAG_BH;
    float* op = out + (size_t)bh * (CH * T_LEN);

    // per-wave slice bases: sl(st) = st*4 + wave; 64-s tile stride = 4096 halves
    const _Float16* kfp = kf + (size_t)bh * FRAG_BH + wave * 1024 + lane * 8;
    const _Float16* vfp = vf + (size_t)bh * FRAG_BH + wave * 1024 + lane * 4;

    // Q fragments: block's 32 t, persistent (same for all 4 waves -> L1)
    half8 bq[2][2];
#pragma unroll
    for (int tt = 0; tt < 2; ++tt)
#pragma unroll
        for (int ks = 0; ks < 2; ++ks)
            bq[tt][ks] = *(const half8*)(qf +
                (((size_t)bh * 128 + tile * 2 + tt) * 2 + ks) * 512 + lane * 8);

    const floatx4 fzero = {0.f, 0.f, 0.f, 0.f};
    floatx4 oacc[4][2];                 // [ct][tt]; c = ct*16+quad*4+r, t = tt*16+l15
#pragma unroll
    for (int ct = 0; ct < 4; ++ct)
#pragma unroll
        for (int tt = 0; tt < 2; ++tt) oacc[ct][tt] = fzero;
    float lsum[2] = {0.f, 0.f};         // per-lane partial denominators

    half8 akA[2], akB[2];    // K slice frags (A-operand, 16x16x32)
    half4 bvA[4], bvB[4];    // V slice frags (A-operand, 16x16x16)

    auto load_kv = [&](half8 (&ak)[2], half4 (&bv)[4], int st) {
        const _Float16* kp = kfp + (size_t)st * 4096;
        ak[0] = *(const half8*)kp;
        ak[1] = *(const half8*)(kp + 512);
        const _Float16* vp = vfp + (size_t)st * 4096;
#pragma unroll
        for (int ct = 0; ct < 4; ++ct)
            bv[ct] = *(const half4*)(vp + ct * 256);
    };

    // one s-tile: prefetch next slice, then per tt: QK -> exp (in-register) -> PV
    auto body = [&](half8 (&akC)[2], half4 (&bvC)[4],
                    half8 (&akN)[2], half4 (&bvN)[4], int st) {
        if (st < 31) load_kv(akN, bvN, st + 1);
#pragma unroll
        for (int tt = 0; tt < 2; ++tt) {
            floatx4 sacc = fzero;
#pragma unroll
            for (int ks = 0; ks < 2; ++ks)
                sacc = __builtin_amdgcn_mfma_f32_16x16x32_f16(
                    akC[ks], bq[tt][ks], sacc, 0, 0, 0);
            // lane owns P[t = tt*16+l15][s_local = quad*4 + r] -> exactly the
            // 16x16x16 B-frag (t = l15, k = quad*4 + e): zero data movement.
            float e0 = __builtin_amdgcn_exp2f(sacc[0]);
            float e1 = __builtin_amdgcn_exp2f(sacc[1]);
            float e2 = __builtin_amdgcn_exp2f(sacc[2]);
            float e3 = __builtin_amdgcn_exp2f(sacc[3]);
            lsum[tt] += (e0 + e1) + (e2 + e3);
            fp16x2 p01 = __builtin_amdgcn_cvt_pkrtz(e0, e1);
            fp16x2 p23 = __builtin_amdgcn_cvt_pkrtz(e2, e3);
            uintx2 uu;
            uu[0] = __builtin_bit_cast(unsigned, p01);
            uu[1] = __builtin_bit_cast(unsigned, p23);
            half4 pb = __builtin_bit_cast(half4, uu);
#pragma unroll
            for (int ct = 0; ct < 4; ++ct)
                oacc[ct][tt] = __builtin_amdgcn_mfma_f32_16x16x16f16(
                    bvC[ct], pb, oacc[ct][tt], 0, 0, 0);
        }
    };

    load_kv(akA, bvA, 0);
    for (int st = 0; st < 32; st += 2) {
        body(akA, bvA, akB, bvB, st);
        body(akB, bvB, akA, bvA, st + 1);
    }

    // ---- epilogue: cross-quad + cross-wave reduction of l and O, then store ------
    // quad-reduce lsum (lanes l, l^16, l^32, l^48 share t = l15)
#pragma unroll
    for (int tt = 0; tt < 2; ++tt) {
        float v = lsum[tt];
        v += __shfl_xor(v, 16, 64);
        v += __shfl_xor(v, 32, 64);
        lsum[tt] = v;
    }
    if (quad == 0) {
#pragma unroll
        for (int tt = 0; tt < 2; ++tt) Lred[wave][tt * 16 + l15] = lsum[tt];
    }
    __syncthreads();
    if (tid < 32)
        Lfin[tid] = (Lred[0][tid] + Lred[1][tid]) + (Lred[2][tid] + Lred[3][tid]);

    // O: reduce 4 wave-partials chunk-by-chunk over ct (16 c rows at a time)
    for (int ct = 0; ct < 4; ++ct) {
        __syncthreads();              // chunk-0: also publishes Lfin; later: Os reuse
#pragma unroll
        for (int tt = 0; tt < 2; ++tt)
            *(floatx4*)&Os[wave][tt * 16 + l15][quad * 4] = oacc[ct][tt];
        __syncthreads();
        const int t  = tid & 31;
        const int c2 = (tid >> 5) * 2;
        const float inv = 1.0f / Lfin[t];
#pragma unroll
        for (int j = 0; j < 2; ++j) {
            float v = ((Os[0][t][c2 + j] + Os[1][t][c2 + j]) +
                       (Os[2][t][c2 + j] + Os[3][t][c2 + j])) * inv;
            op[(size_t)(ct * 16 + c2 + j) * T_LEN + t0 + t] = v;
        }
    }
}

extern "C" void kernel_launch(void* const* d_in, const int* in_sizes, int n_in,
                              void* d_out, int out_size, void* d_ws, size_t ws_size,
                              hipStream_t stream) {
    const float* qkv     = (const float*)d_in[0];
    const float* rescale = (const float*)d_in[1];
    float* out = (float*)d_out;
    _Float16* ws = (_Float16*)d_ws;   // needs 3*32*131072*2 B = 25.2 MB

    prep_kernel<<<dim3(32, BH), dim3(256), 0, stream>>>(qkv, rescale, ws);
    attn_kernel<<<dim3(T_LEN / QTILE * BH), dim3(256), 0, stream>>>(ws, out);
}

// Round 8
// 133.088 us; speedup vs baseline: 1.0853x; 1.0853x over previous
//
#include <hip/hip_runtime.h>
#include <stdint.h>

typedef _Float16 half8 __attribute__((ext_vector_type(8)));
typedef _Float16 half4 __attribute__((ext_vector_type(4)));
typedef __fp16   fp16x2 __attribute__((ext_vector_type(2)));
typedef float    floatx4 __attribute__((ext_vector_type(4)));
typedef unsigned uintx2 __attribute__((ext_vector_type(2)));

#define T_LEN 2048
#define CH 64
#define BH 32            // bs * n_heads
#define QTILE 128        // t per block (32 per wave) -> 512 blocks = 2 blocks/CU
#define LDP 72           // prep LDS pad (halves)
#define FRAG_BH 131072   // halves per bh per tensor (64*2048)

// ---------------- pass 1: fp32 -> fp16, reorder into MFMA fragment order ----------
// Q pre-scaled by 0.125 * rescale * log2(e) so attention does raw exp2.
// QF/KF[bh][g][ks][lane][8]: g = t(or s)>>4, element = X[c = ks*32+quad*8+j][t = g*16+l15]
// VF[bh][sl][ct][lane][4]  (16x16x16 A-frag order):
//   element = V[c = ct*16 + l15][s = sl*16 + quad*4 + e]
__global__ __launch_bounds__(256, 2)
void prep_kernel(const float* __restrict__ qkv, const float* __restrict__ rescale,
                 _Float16* __restrict__ ws)
{
    __shared__ _Float16 Qs[64][LDP];   // [t][c]
    __shared__ _Float16 Ks[64][LDP];   // [s][c]
    __shared__ _Float16 Vs[64][LDP];   // [c][s]

    const int tid  = threadIdx.x;
    const int bh   = blockIdx.y;
    const int tile = blockIdx.x;       // 64-element tile along t/s
    const int x0   = tile * 64;

    const float qscale = 0.125f * 1.4426950408889634f * rescale[0];

    const float* qp = qkv + (size_t)(bh >> 3) * (1536 * T_LEN)
                          + (size_t)(bh & 7) * (192 * T_LEN);
    const float* kp = qp + 64 * T_LEN;
    const float* vp = qp + 128 * T_LEN;

    // Q,K: 4x4 register-block transpose [c][t] -> [t][c]
    {
        const int a4 = (tid & 15) * 4;
        const int c4 = (tid >> 4) * 4;
        float4 rq[4], rk[4];
#pragma unroll
        for (int i = 0; i < 4; ++i) {
            rq[i] = *(const float4*)(qp + (size_t)(c4 + i) * T_LEN + x0 + a4);
            rk[i] = *(const float4*)(kp + (size_t)(c4 + i) * T_LEN + x0 + a4);
        }
#pragma unroll
        for (int j = 0; j < 4; ++j) {
            half4 hq, hk;
#pragma unroll
            for (int i = 0; i < 4; ++i) {
                hq[i] = (_Float16)((&rq[i].x)[j] * qscale);
                hk[i] = (_Float16)((&rk[i].x)[j]);
            }
            *(half4*)&Qs[a4 + j][c4] = hq;
            *(half4*)&Ks[a4 + j][c4] = hk;
        }
        // V natural [c][s]
        const int s4 = (tid & 15) * 4;
        const int cv = tid >> 4;
#pragma unroll
        for (int i = 0; i < 4; ++i) {
            const int c = cv + 16 * i;
            float4 r = *(const float4*)(vp + (size_t)c * T_LEN + x0 + s4);
            half4 h; h[0]=(_Float16)r.x; h[1]=(_Float16)r.y; h[2]=(_Float16)r.z; h[3]=(_Float16)r.w;
            *(half4*)&Vs[c][s4] = h;
        }
    }
    __syncthreads();

    const int lane = tid & 63, wave = tid >> 6;
    const int l15 = lane & 15, quad = lane >> 4;
    _Float16* qf = ws;
    _Float16* kf = ws + (size_t)BH * FRAG_BH;
    _Float16* vf = ws + (size_t)2 * BH * FRAG_BH;

#pragma unroll
    for (int ks = 0; ks < 2; ++ks) {
        half8 hq = *(const half8*)&Qs[wave * 16 + l15][ks * 32 + quad * 8];
        half8 hk = *(const half8*)&Ks[wave * 16 + l15][ks * 32 + quad * 8];
        const size_t gqk = (((size_t)bh * 128 + tile * 4 + wave) * 2 + ks) * 512 + lane * 8;
        *(half8*)(qf + gqk) = hq;
        *(half8*)(kf + gqk) = hk;
    }
    // V fragments: wave w handles sl = tile*4 + w (16 s values)
#pragma unroll
    for (int ct = 0; ct < 4; ++ct) {
        half4 hv = *(const half4*)&Vs[ct * 16 + l15][wave * 16 + quad * 4];
        *(half4*)(vf + (size_t)bh * FRAG_BH
                     + ((size_t)(tile * 4 + wave) * 4 + ct) * 256 + lane * 4) = hv;
    }
}

// async global->LDS, 16B per lane: dest = lds_base(uniform) + lane*16
__device__ __forceinline__ void gload16(const _Float16* g, _Float16* l) {
    __builtin_amdgcn_global_load_lds(
        (const __attribute__((address_space(1))) void*)g,
        (__attribute__((address_space(3))) void*)l, 16, 0, 0);
}

// ---------------- pass 2: attention = R3 geometry + R6 in-register softmax --------
// R7 post-mortem: occupancy 23->34% yet 23% SLOWER (AI halved, VMEM doubled) --
// "more waves" refuted 3x. The 47.7us wall of R0/R3 is the serial per-tile chain
// QK -> exp -> Pt-LDS-round-trip -> PV. R6 proved the escape (mis-deployed there):
// with V as the A-operand of mfma_16x16x16, QK's D layout (t=l15, s=quad*4+r) IS
// PV's B-fragment -- softmax never leaves registers, in ANY geometry.
// This round: QTILE=128 / 512 blocks / staged dbuf K+V (16KB per block-iter,
// minimal-traffic config) / one barrier per iter / XCD swizzle -- all verified --
// with Pt + its 3.1M conflict cycles + ~24 DS ops/iter + ones-MFMA all DELETED.
// Per mt: QK(4 MFMA) -> exp2/pack (VALU) -> PV(8x 16x16x16, acc over mt).
// Denominator = VALU adds + 2 shfl_xor at the end; epilogue uses no LDS.
__global__ __launch_bounds__(256, 2)
void attn_kernel(const _Float16* __restrict__ ws, float* __restrict__ out)
{
    __shared__ _Float16 Kb[2][4096];      // [buf][8KB tile]
    __shared__ _Float16 Vb[2][4096];

    const int tid  = threadIdx.x;
    const int wave = tid >> 6;
    const int lane = tid & 63;
    const int l15  = lane & 15;
    const int quad = lane >> 4;

    // XCD-aware decode: all 16 t-tiles of one bh on ONE XCD (4 bh x 512KB = 2MB/XCD L2)
    const int bid  = blockIdx.x;        // 0..511
    const int xcd  = bid & 7;
    const int slot = bid >> 3;          // 0..63
    const int bh   = (slot >> 4) * 8 + xcd;
    const int tile = slot & 15;
    const int t0   = tile * QTILE;

    const _Float16* qf = ws;
    const _Float16* kf = ws + (size_t)BH * FRAG_BH;
    const _Float16* vf = ws + (size_t)2 * BH * FRAG_BH;
    float* op = out + (size_t)bh * (CH * T_LEN);

    const _Float16* ktile = kf + (size_t)bh * FRAG_BH;   // + st*4096 per tile
    const _Float16* vtile = vf + (size_t)bh * FRAG_BH;

    // stage tile st into buf: 16KB split over 4 waves, 4 async insts/wave
    auto stage = [&](int st, int buf) {
        const _Float16* kg = ktile + (size_t)st * 4096 + wave * 1024 + lane * 8;
        const _Float16* vg = vtile + (size_t)st * 4096 + wave * 1024 + lane * 8;
        _Float16* kl = &Kb[buf][wave * 1024];
        _Float16* vl = &Vb[buf][wave * 1024];
        gload16(kg,       kl);
        gload16(kg + 512, kl + 512);
        gload16(vg,       vl);
        gload16(vg + 512, vl + 512);
    };

    // Q fragments: persistent (Q pre-scaled in prep); 32 t/wave = 2 t-groups
    half8 bq[2][2];
#pragma unroll
    for (int tb = 0; tb < 2; ++tb)
#pragma unroll
        for (int ks = 0; ks < 2; ++ks)
            bq[tb][ks] = *(const half8*)(qf +
                (((size_t)bh * 128 + tile * 8 + wave * 2 + tb) * 2 + ks) * 512 + lane * 8);

    const floatx4 fzero = {0.f, 0.f, 0.f, 0.f};
    floatx4 oacc[4][2];                 // [ct][tb]; c = ct*16+quad*4+r, t = tb-group,l15
#pragma unroll
    for (int ct = 0; ct < 4; ++ct)
#pragma unroll
        for (int tb = 0; tb < 2; ++tb) oacc[ct][tb] = fzero;
    float lsum[2] = {0.f, 0.f};         // per-lane partial denominators

    half8 ak[4][2];      // K frags of current tile (A-operand, 16x16x32)
    half4 bv[4][4];      // V frags [mt][ct] of current tile (A-operand, 16x16x16)

    auto read_ak = [&](int buf) {
#pragma unroll
        for (int mt = 0; mt < 4; ++mt)
#pragma unroll
            for (int ks = 0; ks < 2; ++ks)
                ak[mt][ks] = *(const half8*)&Kb[buf][(mt * 2 + ks) * 512 + lane * 8];
    };
    auto read_bv = [&](int buf) {
#pragma unroll
        for (int mt = 0; mt < 4; ++mt)
#pragma unroll
            for (int ct = 0; ct < 4; ++ct)
                bv[mt][ct] = *(const half4*)&Vb[buf][mt * 1024 + ct * 256 + lane * 4];
    };

    // tile st: per mt-slice QK -> in-register exp -> PV (no LDS, no shuffle)
    auto body = [&]() {
#pragma unroll
        for (int mt = 0; mt < 4; ++mt) {
            floatx4 s0 = fzero, s1 = fzero;
#pragma unroll
            for (int ks = 0; ks < 2; ++ks) {
                s0 = __builtin_amdgcn_mfma_f32_16x16x32_f16(ak[mt][ks], bq[0][ks], s0, 0, 0, 0);
                s1 = __builtin_amdgcn_mfma_f32_16x16x32_f16(ak[mt][ks], bq[1][ks], s1, 0, 0, 0);
            }
            // lane holds P[t = g*16+l15][s = st*64 + mt*16 + quad*4 + r]
            float a0 = __builtin_amdgcn_exp2f(s0[0]);
            float a1 = __builtin_amdgcn_exp2f(s0[1]);
            float a2 = __builtin_amdgcn_exp2f(s0[2]);
            float a3 = __builtin_amdgcn_exp2f(s0[3]);
            float b0 = __builtin_amdgcn_exp2f(s1[0]);
            float b1 = __builtin_amdgcn_exp2f(s1[1]);
            float b2 = __builtin_amdgcn_exp2f(s1[2]);
            float b3 = __builtin_amdgcn_exp2f(s1[3]);
            lsum[0] += (a0 + a1) + (a2 + a3);
            lsum[1] += (b0 + b1) + (b2 + b3);
            uintx2 u0, u1;
            u0[0] = __builtin_bit_cast(unsigned, __builtin_amdgcn_cvt_pkrtz(a0, a1));
            u0[1] = __builtin_bit_cast(unsigned, __builtin_amdgcn_cvt_pkrtz(a2, a3));
            u1[0] = __builtin_bit_cast(unsigned, __builtin_amdgcn_cvt_pkrtz(b0, b1));
            u1[1] = __builtin_bit_cast(unsigned, __builtin_amdgcn_cvt_pkrtz(b2, b3));
            half4 p0 = __builtin_bit_cast(half4, u0);   // B-frag: col=t(l15), k=quad*4+e
            half4 p1 = __builtin_bit_cast(half4, u1);
#pragma unroll
            for (int ct = 0; ct < 4; ++ct) {
                oacc[ct][0] = __builtin_amdgcn_mfma_f32_16x16x16f16(
                    bv[mt][ct], p0, oacc[ct][0], 0, 0, 0);
                oacc[ct][1] = __builtin_amdgcn_mfma_f32_16x16x16f16(
                    bv[mt][ct], p1, oacc[ct][1], 0, 0, 0);
            }
        }
    };

    // ---- prologue
    stage(0, 0);
    __syncthreads();              // tile 0 in buf 0
    read_ak(0);
    read_bv(0);
    stage(1, 1);                  // full tile-0 compute to land

    // ---- main loop: one barrier per tile
    for (int st = 0; st < 32; ++st) {
        const int cur = st & 1;
        if (st >= 1 && st < 31) stage(st + 1, cur ^ 1);  // buf freed at last barrier
        body();                   // tile st from registers
        if (st < 31) {
            __syncthreads();      // tile st+1 landed; reg reads of buf cur done
            read_ak(cur ^ 1);
            read_bv(cur ^ 1);
        }
    }

    // ---- epilogue: quad-reduce denominators, scale, store (no LDS) -------------
    float linv[2];
#pragma unroll
    for (int tb = 0; tb < 2; ++tb) {
        float v = lsum[tb];
        v += __shfl_xor(v, 16, 64);
        v += __shfl_xor(v, 32, 64);
        linv[tb] = 1.0f / v;
    }
    // oacc[ct][tb][r] = O[c = ct*16 + quad*4 + r][t = t0 + wave*32 + tb*16 + l15]
#pragma unroll
    for (int tb = 0; tb < 2; ++tb) {
        const int t = t0 + wave * 32 + tb * 16 + l15;
#pragma unroll
        for (int ct = 0; ct < 4; ++ct)
#pragma unroll
            for (int r = 0; r < 4; ++r)
                op[(size_t)(ct * 16 + quad * 4 + r) * T_LEN + t] = oacc[ct][tb][r] * linv[tb];
    }
}

extern "C" void kernel_launch(void* const* d_in, const int* in_sizes, int n_in,
                              void* d_out, int out_size, void* d_ws, size_t ws_size,
                              hipStream_t stream) {
    const float* qkv     = (const float*)d_in[0];
    const float* rescale = (const float*)d_in[1];
    float* out = (float*)d_out;
    _Float16* ws = (_Float16*)d_ws;   // needs 3*32*131072*2 B = 25.2 MB

    prep_kernel<<<dim3(32, BH), dim3(256), 0, stream>>>(qkv, rescale, ws);
    attn_kernel<<<dim3(T_LEN / QTILE * BH), dim3(256), 0, stream>>>(ws, out);
}